// Round 11
// baseline (1335.360 us; speedup 1.0000x reference)
//
#include <hip/hip_runtime.h>

#define M_NODES 16384
#define NNBR 32
#define RREL 237
#define ATTN_SCALE 0.25f   // (128/8)^-0.5
#define LN_EPS 1e-5f
#define NBLK 1024          // 4 blocks/CU x 256 CUs — co-residency by construction

typedef float float4v __attribute__((ext_vector_type(4)));
typedef unsigned int uint4v __attribute__((ext_vector_type(4)));
typedef short short8 __attribute__((ext_vector_type(8)));
typedef float floatx4 __attribute__((ext_vector_type(4)));

__device__ __forceinline__ float bfu2f(unsigned short u) {
    return __builtin_bit_cast(float, ((unsigned int)u) << 16);
}
__device__ __forceinline__ unsigned short f2bfu(float f) {
    unsigned int x = __builtin_bit_cast(unsigned int, f);
    unsigned int lsb = (x >> 16) & 1u;
    x += 0x7fffu + lsb;                 // round-to-nearest-even
    return (unsigned short)(x >> 16);
}
__device__ __forceinline__ unsigned int pack2(float a, float b) {
    return (unsigned int)f2bfu(a) | ((unsigned int)f2bfu(b) << 16);
}
__device__ __forceinline__ float unpk_lo(unsigned int u) {
    return __builtin_bit_cast(float, u << 16);
}
__device__ __forceinline__ float unpk_hi(unsigned int u) {
    return __builtin_bit_cast(float, u & 0xffff0000u);
}

// Device-wide sense-reversing barrier. bar[0]=counter, bar[1]=generation.
// All NBLK blocks are co-resident (4/CU, enforced by __launch_bounds__ + LDS).
__device__ __forceinline__ void gbar(unsigned* bar) {
    __threadfence();                   // release: my global writes visible device-wide
    __syncthreads();
    if (threadIdx.x == 0) {
        unsigned gen = __hip_atomic_load(&bar[1], __ATOMIC_ACQUIRE, __HIP_MEMORY_SCOPE_AGENT);
        unsigned a = __hip_atomic_fetch_add(&bar[0], 1u, __ATOMIC_ACQ_REL, __HIP_MEMORY_SCOPE_AGENT);
        if (a == NBLK - 1) {
            __hip_atomic_store(&bar[0], 0u, __ATOMIC_RELAXED, __HIP_MEMORY_SCOPE_AGENT);
            __hip_atomic_fetch_add(&bar[1], 1u, __ATOMIC_RELEASE, __HIP_MEMORY_SCOPE_AGENT);
        } else {
            while (__hip_atomic_load(&bar[1], __ATOMIC_ACQUIRE, __HIP_MEMORY_SCOPE_AGENT) == gen)
                __builtin_amdgcn_s_sleep(2);
        }
    }
    __syncthreads();
    __threadfence();                   // acquire: don't read stale lines
}

// ===========================================================================
// MEGA KERNEL — all four r10 phases, one dispatch, 3 device barriers.
// ===========================================================================
__global__ __launch_bounds__(256, 4) void mega(
    const float* __restrict__ entity,
    const int* __restrict__ nidx, const int* __restrict__ nrel,
    const int* __restrict__ nmask,
    const float* __restrict__ Wq, const float* __restrict__ bq,
    const float* __restrict__ Wk, const float* __restrict__ bk,
    const float* __restrict__ Wv, const float* __restrict__ bv,
    const float* __restrict__ Wo, const float* __restrict__ bo,
    const float* __restrict__ rel_table,
    const float* __restrict__ gamma_, const float* __restrict__ beta_,
    unsigned short* __restrict__ WqT, unsigned short* __restrict__ WkT,
    unsigned short* __restrict__ WvT, unsigned short* __restrict__ WoT,
    unsigned short* __restrict__ EQb, unsigned short* __restrict__ EKV,
    unsigned short* __restrict__ RKb, unsigned short* __restrict__ OATb,
    unsigned* __restrict__ bar, float* __restrict__ OUT) {
    __shared__ __align__(16) unsigned short lw[128 * 136];   // 34.8 KB, re-aliased per phase

    int bx = blockIdx.x;
    int t = threadIdx.x;

    // ---------------- phase 0: weight transpose+convert (blocks 0..31) ------
    if (bx < 32) {
        int mat  = bx >> 3;
        int slab = bx & 7;
        const float* W = (mat == 0) ? Wq : (mat == 1) ? Wk : (mat == 2) ? Wv : Wo;
        unsigned short* WT = (mat == 0) ? WqT : (mat == 1) ? WkT : (mat == 2) ? WvT : WoT;
        #pragma unroll
        for (int i = 0; i < 8; ++i) {
            int idx = t + 256 * i;
            int r = slab * 16 + (idx >> 7);
            int c = idx & 127;
            WT[c * 128 + r] = f2bfu(W[r * 128 + c]);
        }
    }
    gbar(bar);

    // ---------------- phase 1: projections (blocks 0..511) ------------------
    if (bx < 512) {
        int y = bx >> 7;
        const float* A; const unsigned short* WT; const float* bias; int arows;
        unsigned short* outb; int ostride, ooff;
        if (y == 0)      { A = entity;    WT = WqT; bias = bq;      arows = M_NODES; outb = EQb; ostride = 128; ooff = 0;   }
        else if (y == 1) { A = entity;    WT = WkT; bias = nullptr; arows = M_NODES; outb = EKV; ostride = 256; ooff = 0;   }
        else if (y == 2) { A = entity;    WT = WvT; bias = bv;      arows = M_NODES; outb = EKV; ostride = 256; ooff = 128; }
        else             { A = rel_table; WT = WkT; bias = bk;      arows = RREL;    outb = RKb; ostride = 128; ooff = 0;   }
        int rbase = (bx & 127) * 128;
        if (rbase < arows) {
            #pragma unroll
            for (int i = 0; i < 8; ++i) {
                int ci = t + 256 * i;
                int r  = ci >> 4;
                int c8 = ci & 15;
                *(short8*)&lw[r * 136 + c8 * 8] = *(const short8*)&WT[r * 128 + c8 * 8];
            }
            __syncthreads();

            int wave = t >> 6, lane = t & 63;
            int lm = lane & 15, quad = lane >> 4;
            int m0 = rbase + wave * 32;

            floatx4 acc[2][8];
            #pragma unroll
            for (int i = 0; i < 2; ++i)
                #pragma unroll
                for (int c = 0; c < 8; ++c) acc[i][c] = (floatx4){0.f, 0.f, 0.f, 0.f};

            int r0 = m0 + lm;      if (r0 >= arows) r0 = arows - 1;
            int r1 = m0 + 16 + lm; if (r1 >= arows) r1 = arows - 1;

            #pragma unroll
            for (int ks = 0; ks < 4; ++ks) {
                int koff = ks * 32 + quad * 8;
                float4v f00 = *(const float4v*)&A[r0 * 128 + koff];
                float4v f01 = *(const float4v*)&A[r0 * 128 + koff + 4];
                float4v f10 = *(const float4v*)&A[r1 * 128 + koff];
                float4v f11 = *(const float4v*)&A[r1 * 128 + koff + 4];
                short8 a0, a1;
                #pragma unroll
                for (int j = 0; j < 4; ++j) {
                    a0[j]     = (short)f2bfu(f00[j]);
                    a0[4 + j] = (short)f2bfu(f01[j]);
                    a1[j]     = (short)f2bfu(f10[j]);
                    a1[4 + j] = (short)f2bfu(f11[j]);
                }
                #pragma unroll
                for (int c = 0; c < 8; ++c) {
                    short8 b = *(const short8*)&lw[(c * 16 + lm) * 136 + koff];
                    acc[0][c] = __builtin_amdgcn_mfma_f32_16x16x32_bf16(a0, b, acc[0][c], 0, 0, 0);
                    acc[1][c] = __builtin_amdgcn_mfma_f32_16x16x32_bf16(a1, b, acc[1][c], 0, 0, 0);
                }
            }

            #pragma unroll
            for (int c = 0; c < 8; ++c) {
                int col = c * 16 + lm;
                float bb = bias ? bias[col] : 0.0f;
                #pragma unroll
                for (int i = 0; i < 2; ++i) {
                    int rb = m0 + i * 16 + quad * 4;
                    #pragma unroll
                    for (int j = 0; j < 4; ++j) {
                        int r = rb + j;
                        if (r < arows) outb[r * ostride + ooff + col] = f2bfu(acc[i][c][j] + bb);
                    }
                }
            }
        }
    }
    gbar(bar);

    // ---------------- phase 2: attention (4096 virtual blocks) --------------
    {
        float* Pl = (float*)lw;                         // [4][8][33] = 4224 B
        int* mixp = (int*)((char*)lw + 4224);           // [4][32]    = 512 B
        int w = t >> 6, l = t & 63;
        int half = l >> 5, n = l & 31;
        int dgrp = l & 15, ngrp = l >> 4;
        int h2 = dgrp >> 1;
        for (int vb = bx; vb < 4096; vb += NBLK) {
            int m = vb * 4 + w;
            int mk = nmask[m * NNBR + n];
            int ix = nidx[m * NNBR + n];
            int ir = nrel[m * NNBR + n];
            if (!mk) { ix = 0; ir = 0; }
            ix = ix < 0 ? 0 : (ix > M_NODES - 1 ? M_NODES - 1 : ix);
            ir = ir < 0 ? 0 : (ir > RREL - 1 ? RREL - 1 : ir);
            if (l < 32) mixp[w * 32 + l] = ix;          // wave-private

            const unsigned short* qp = &EQb[m * 128 + half * 64];
            const unsigned short* kp = &EKV[ix * 256 + half * 64];
            const unsigned short* rp = &RKb[ir * 128 + half * 64];
            float acc[4] = {0.f, 0.f, 0.f, 0.f};
            #pragma unroll
            for (int c = 0; c < 8; ++c) {
                short8 q8 = *(const short8*)&qp[c * 8];
                short8 k8 = *(const short8*)&kp[c * 8];
                short8 r8 = *(const short8*)&rp[c * 8];
                int hh = c >> 1;
                #pragma unroll
                for (int j = 0; j < 8; ++j)
                    acc[hh] += bfu2f((unsigned short)q8[j]) *
                               (bfu2f((unsigned short)k8[j]) + bfu2f((unsigned short)r8[j]));
            }
            #pragma unroll
            for (int hh = 0; hh < 4; ++hh) {
                float lf = acc[hh] * ATTN_SCALE;
                if (!mk) lf = -1e30f;
                float mx = lf;
                #pragma unroll
                for (int off = 16; off >= 1; off >>= 1) mx = fmaxf(mx, __shfl_xor(mx, off, 32));
                float p = __expf(lf - mx);
                float s = p;
                #pragma unroll
                for (int off = 16; off >= 1; off >>= 1) s += __shfl_xor(s, off, 32);
                Pl[(w * 8 + half * 4 + hh) * 33 + n] = p / s;
            }

            float o[8] = {0.f, 0.f, 0.f, 0.f, 0.f, 0.f, 0.f, 0.f};
            #pragma unroll
            for (int i = 0; i < 8; ++i) {
                int n2 = ngrp + i * 4;
                float pp = Pl[(w * 8 + h2) * 33 + n2];
                int ixx = mixp[w * 32 + n2];
                short8 v8 = *(const short8*)&EKV[ixx * 256 + 128 + dgrp * 8];
                #pragma unroll
                for (int j = 0; j < 8; ++j) o[j] += pp * bfu2f((unsigned short)v8[j]);
            }
            #pragma unroll
            for (int j = 0; j < 8; ++j) {
                o[j] += __shfl_xor(o[j], 16, 64);
                o[j] += __shfl_xor(o[j], 32, 64);
            }
            if (ngrp == 0) {
                uint4v u;
                u[0] = pack2(o[0], o[1]); u[1] = pack2(o[2], o[3]);
                u[2] = pack2(o[4], o[5]); u[3] = pack2(o[6], o[7]);
                *(uint4v*)&OATb[m * 128 + dgrp * 8] = u;
            }
        }
    }
    gbar(bar);

    // ---------------- phase 3: Wo GEMM + residual + LayerNorm (blocks 0..127)
    if (bx < 128) {
        #pragma unroll
        for (int i = 0; i < 8; ++i) {
            int ci = t + 256 * i;
            int r  = ci >> 4;
            int c8 = ci & 15;
            *(short8*)&lw[r * 136 + c8 * 8] = *(const short8*)&WoT[r * 128 + c8 * 8];
        }
        __syncthreads();

        int wave = t >> 6, lane = t & 63;
        int lm = lane & 15, quad = lane >> 4;
        int m0 = bx * 128 + wave * 32;

        floatx4 acc[2][8];
        #pragma unroll
        for (int i = 0; i < 2; ++i)
            #pragma unroll
            for (int c = 0; c < 8; ++c) acc[i][c] = (floatx4){0.f, 0.f, 0.f, 0.f};

        int r0 = m0 + lm, r1 = m0 + 16 + lm;
        #pragma unroll
        for (int ks = 0; ks < 4; ++ks) {
            int koff = ks * 32 + quad * 8;
            short8 a0 = *(const short8*)&OATb[r0 * 128 + koff];
            short8 a1 = *(const short8*)&OATb[r1 * 128 + koff];
            #pragma unroll
            for (int c = 0; c < 8; ++c) {
                short8 b = *(const short8*)&lw[(c * 16 + lm) * 136 + koff];
                acc[0][c] = __builtin_amdgcn_mfma_f32_16x16x32_bf16(a0, b, acc[0][c], 0, 0, 0);
                acc[1][c] = __builtin_amdgcn_mfma_f32_16x16x32_bf16(a1, b, acc[1][c], 0, 0, 0);
            }
        }

        float bb[8], gg[8], be[8];
        #pragma unroll
        for (int c = 0; c < 8; ++c) {
            int col = c * 16 + lm;
            bb[c] = bo[col]; gg[c] = gamma_[col]; be[c] = beta_[col];
        }
        #pragma unroll
        for (int i = 0; i < 2; ++i) {
            #pragma unroll
            for (int j = 0; j < 4; ++j) {
                int r = m0 + i * 16 + quad * 4 + j;
                float y[8];
                float s1 = 0.f, s2 = 0.f;
                #pragma unroll
                for (int c = 0; c < 8; ++c) {
                    float v = acc[i][c][j] + bb[c] + entity[r * 128 + c * 16 + lm];
                    y[c] = v; s1 += v; s2 += v * v;
                }
                #pragma unroll
                for (int off = 8; off >= 1; off >>= 1) {
                    s1 += __shfl_xor(s1, off, 16);
                    s2 += __shfl_xor(s2, off, 16);
                }
                float mu  = s1 * (1.0f / 128.0f);
                float var = fmaxf(s2 * (1.0f / 128.0f) - mu * mu, 0.0f);
                float rs  = rsqrtf(var + LN_EPS);
                #pragma unroll
                for (int c = 0; c < 8; ++c)
                    OUT[r * 128 + c * 16 + lm] = (y[c] - mu) * rs * gg[c] + be[c];
            }
        }
    }
}

// ===========================================================================
// FALLBACK (round-5 fused kernel, ~314 µs) — used if ws too small
// ===========================================================================
__global__ __launch_bounds__(256, 6) void rga_fused(
    const float* __restrict__ entity,
    const int* __restrict__ nidx,
    const int* __restrict__ nrel,
    const int* __restrict__ nmask,
    const float* __restrict__ Wq, const float* __restrict__ bq,
    const float* __restrict__ Wk, const float* __restrict__ bk,
    const float* __restrict__ Wv, const float* __restrict__ bv,
    const float* __restrict__ Wo, const float* __restrict__ bo,
    const float* __restrict__ rel_table,
    const float* __restrict__ gamma_, const float* __restrict__ beta_,
    float* __restrict__ outp) {
    __shared__ __align__(16) float er[128];
    __shared__ __align__(16) float qv[128];
    __shared__ float qb[8];
    __shared__ __align__(16) float qk[8 * 132];
    __shared__ __align__(16) unsigned int nbvp[32 * 68];
    __shared__ float Lg[8][33];
    __shared__ __align__(16) float pv[8 * 132];
    __shared__ __align__(16) float oat[128];
    __shared__ float ypart[2][128];
    __shared__ float red[4];
    __shared__ int midx[32], mrel[32], mmask[32];

    int m = blockIdx.x;
    int t = threadIdx.x;

    if (t < 32) {
        int mk = nmask[m * NNBR + t];
        int ix = nidx[m * NNBR + t];
        int ir = nrel[m * NNBR + t];
        if (!mk) { ix = 0; ir = 0; }
        ix = ix < 0 ? 0 : (ix > M_NODES - 1 ? M_NODES - 1 : ix);
        ir = ir < 0 ? 0 : (ir > RREL - 1 ? RREL - 1 : ir);
        mmask[t] = mk; midx[t] = ix; mrel[t] = ir;
    }
    if (t >= 128) er[t - 128] = entity[m * 128 + (t - 128)];
    __syncthreads();

    {
        int half = t >> 7, d = t & 127, j0 = half * 64;
        const float4v* e4 = (const float4v*)&er[j0];
        float acc = 0.f;
        #pragma unroll 4
        for (int c = 0; c < 16; ++c) {
            float4v ev = e4[c];
            #pragma unroll
            for (int k = 0; k < 4; ++k)
                acc += ev[k] * Wq[(j0 + c * 4 + k) * 128 + d];
        }
        ypart[half][d] = acc;
    }
    __syncthreads();
    if (t < 128) qv[t] = ypart[0][t] + ypart[1][t] + bq[t];
    __syncthreads();

    #pragma unroll
    for (int rep = 0; rep < 4; ++rep) {
        int o = rep * 256 + t;
        int h = o >> 7, j = o & 127;
        const float4v* wr = (const float4v*)&Wk[j * 128 + h * 16];
        const float4v* q4 = (const float4v*)&qv[h * 16];
        float s = 0.f;
        #pragma unroll
        for (int c = 0; c < 4; ++c) {
            float4v ww = wr[c], q = q4[c];
            #pragma unroll
            for (int k = 0; k < 4; ++k) s += ww[k] * q[k];
        }
        qk[h * 132 + j] = s;
    }
    if (t < 8) {
        float s = 0.f;
        #pragma unroll
        for (int dh = 0; dh < 16; ++dh) s += qv[t * 16 + dh] * bk[t * 16 + dh];
        qb[t] = s;
    }
    __syncthreads();

    {
        int n = t >> 3, c16 = t & 7, j0 = c16 * 16;
        int ix = midx[n], ir = mrel[n];
        const float4v* ep = (const float4v*)&entity[ix * 128 + j0];
        const float4v* rp = (const float4v*)&rel_table[ir * 128 + j0];
        float ev[16], kv[16];
        #pragma unroll
        for (int c = 0; c < 4; ++c) {
            float4v e4 = ep[c], r4 = rp[c];
            #pragma unroll
            for (int k = 0; k < 4; ++k) {
                ev[c * 4 + k] = e4[k];
                kv[c * 4 + k] = e4[k] + r4[k];
            }
        }
        uint4v u0, u1;
        #pragma unroll
        for (int k = 0; k < 4; ++k) u0[k] = pack2(ev[2 * k], ev[2 * k + 1]);
        #pragma unroll
        for (int k = 0; k < 4; ++k) u1[k] = pack2(ev[8 + 2 * k], ev[9 + 2 * k]);
        *(uint4v*)&nbvp[n * 68 + c16 * 8]     = u0;
        *(uint4v*)&nbvp[n * 68 + c16 * 8 + 4] = u1;
        float acc[8];
        #pragma unroll
        for (int h = 0; h < 8; ++h) {
            const float4v* qrow = (const float4v*)&qk[h * 132 + j0];
            float s = 0.f;
            #pragma unroll
            for (int c = 0; c < 4; ++c) {
                float4v q = qrow[c];
                #pragma unroll
                for (int k = 0; k < 4; ++k) s += q[k] * kv[c * 4 + k];
            }
            acc[h] = s;
        }
        #pragma unroll
        for (int off = 1; off < 8; off <<= 1) {
            #pragma unroll
            for (int h = 0; h < 8; ++h) acc[h] += __shfl_xor(acc[h], off, 8);
        }
        if (c16 == 0) {
            #pragma unroll
            for (int h = 0; h < 8; ++h) {
                float lf = (acc[h] + qb[h]) * ATTN_SCALE;
                if (!mmask[n]) lf = -1e30f;
                Lg[h][n] = lf;
            }
        }
    }
    __syncthreads();

    {
        int h = t >> 5, n = t & 31;
        float lf = Lg[h][n];
        float mx = lf;
        #pragma unroll
        for (int off = 16; off >= 1; off >>= 1) mx = fmaxf(mx, __shfl_xor(mx, off, 32));
        float p = __expf(lf - mx);
        float s = p;
        #pragma unroll
        for (int off = 16; off >= 1; off >>= 1) s += __shfl_xor(s, off, 32);
        Lg[h][n] = p / s;
    }
    __syncthreads();

    {
        int h = t >> 5, c4 = t & 31;
        float4v a = (float4v){0.f, 0.f, 0.f, 0.f};
        #pragma unroll 8
        for (int n = 0; n < 32; ++n) {
            float p = Lg[h][n];
            unsigned int w0 = nbvp[n * 68 + c4 * 2];
            unsigned int w1 = nbvp[n * 68 + c4 * 2 + 1];
            a[0] += p * unpk_lo(w0);
            a[1] += p * unpk_hi(w0);
            a[2] += p * unpk_lo(w1);
            a[3] += p * unpk_hi(w1);
        }
        *(float4v*)&pv[h * 132 + c4 * 4] = a;
    }
    __syncthreads();

    {
        int half = t >> 7, d = t & 127, j0 = half * 64;
        int h = d >> 4;
        const float4v* p4 = (const float4v*)&pv[h * 132 + j0];
        float acc = 0.f;
        #pragma unroll 4
        for (int c = 0; c < 16; ++c) {
            float4v p = p4[c];
            #pragma unroll
            for (int k = 0; k < 4; ++k)
                acc += p[k] * Wv[(j0 + c * 4 + k) * 128 + d];
        }
        ypart[half][d] = acc;
    }
    __syncthreads();
    if (t < 128) oat[t] = ypart[0][t] + ypart[1][t] + bv[t];
    __syncthreads();

    {
        int half = t >> 7, d = t & 127, j0 = half * 64;
        const float4v* o4 = (const float4v*)&oat[j0];
        float acc = 0.f;
        #pragma unroll 4
        for (int c = 0; c < 16; ++c) {
            float4v o = o4[c];
            #pragma unroll
            for (int k = 0; k < 4; ++k)
                acc += o[k] * Wo[(j0 + c * 4 + k) * 128 + d];
        }
        ypart[half][d] = acc;
    }
    __syncthreads();

    float x = 0.f;
    if (t < 128) {
        x = er[t] + ypart[0][t] + ypart[1][t] + bo[t];
        float s1 = x, s2 = x * x;
        #pragma unroll
        for (int off = 32; off >= 1; off >>= 1) {
            s1 += __shfl_xor(s1, off, 64);
            s2 += __shfl_xor(s2, off, 64);
        }
        if ((t & 63) == 0) { red[(t >> 6) * 2] = s1; red[(t >> 6) * 2 + 1] = s2; }
    }
    __syncthreads();
    if (t < 128) {
        float mu  = (red[0] + red[2]) * (1.0f / 128.0f);
        float ms  = (red[1] + red[3]) * (1.0f / 128.0f);
        float var = fmaxf(ms - mu * mu, 0.0f);
        float rs  = rsqrtf(var + LN_EPS);
        outp[m * 128 + t] = (x - mu) * rs * gamma_[t] + beta_[t];
    }
}

// ---------------------------------------------------------------------------
extern "C" void kernel_launch(void* const* d_in, const int* in_sizes, int n_in,
                              void* d_out, int out_size, void* d_ws, size_t ws_size,
                              hipStream_t stream) {
    const float* entity    = (const float*)d_in[0];
    const int*   nidx      = (const int*)d_in[1];
    const int*   nrel      = (const int*)d_in[2];
    const int*   nmask     = (const int*)d_in[3];
    const float* Wq        = (const float*)d_in[4];
    const float* bq        = (const float*)d_in[5];
    const float* Wk        = (const float*)d_in[6];
    const float* bk        = (const float*)d_in[7];
    const float* Wv        = (const float*)d_in[8];
    const float* bv        = (const float*)d_in[9];
    const float* Wo        = (const float*)d_in[10];
    const float* bo        = (const float*)d_in[11];
    const float* rel_table = (const float*)d_in[12];
    const float* gamma_    = (const float*)d_in[13];
    const float* beta_     = (const float*)d_in[14];

    // ws layout:
    //   EKV (bf16) 8M     @ 0
    //   EQb (bf16) 4M     @ 8388608
    //   OATb(bf16) 4M     @ 12582912
    //   RKb (bf16) 60672  @ 16777216
    //   WqT/WkT/WvT/WoT 32K each @ 16837888
    //   bar (2 x u32)     @ 16968960
    char* ws = (char*)d_ws;
    unsigned short* EKV  = (unsigned short*)(ws + 0);
    unsigned short* EQb  = (unsigned short*)(ws + 8388608);
    unsigned short* OATb = (unsigned short*)(ws + 12582912);
    unsigned short* RKb  = (unsigned short*)(ws + 16777216);
    unsigned short* WqT  = (unsigned short*)(ws + 16837888);
    unsigned short* WkT  = (unsigned short*)(ws + 16870656);
    unsigned short* WvT  = (unsigned short*)(ws + 16903424);
    unsigned short* WoT  = (unsigned short*)(ws + 16936192);
    unsigned*       bar  = (unsigned*)(ws + 16968960);
    const size_t NEED = 16969024;

    if (ws_size >= NEED) {
        hipMemsetAsync(bar, 0, 8, stream);   // zero barrier state (graph-legal)
        mega<<<dim3(NBLK), 256, 0, stream>>>(
            entity, nidx, nrel, nmask, Wq, bq, Wk, bk, Wv, bv, Wo, bo,
            rel_table, gamma_, beta_,
            WqT, WkT, WvT, WoT, EQb, EKV, RKb, OATb, bar, (float*)d_out);
    } else {
        rga_fused<<<dim3(M_NODES), 256, 0, stream>>>(
            entity, nidx, nrel, nmask, Wq, bq, Wk, bk, Wv, bv, Wo, bo,
            rel_table, gamma_, beta_, (float*)d_out);
    }
}

// Round 12
// 156.579 us; speedup vs baseline: 8.5284x; 8.5284x over previous
//
#include <hip/hip_runtime.h>

#define M_NODES 16384
#define NNBR 32
#define RREL 237
#define ATTN_SCALE 0.25f   // (128/8)^-0.5
#define LN_EPS 1e-5f

typedef float float4v __attribute__((ext_vector_type(4)));
typedef unsigned int uint4v __attribute__((ext_vector_type(4)));
typedef short short8 __attribute__((ext_vector_type(8)));
typedef float floatx4 __attribute__((ext_vector_type(4)));

__device__ __forceinline__ float bfu2f(unsigned short u) {
    return __builtin_bit_cast(float, ((unsigned int)u) << 16);
}
__device__ __forceinline__ unsigned short f2bfu(float f) {
    unsigned int x = __builtin_bit_cast(unsigned int, f);
    unsigned int lsb = (x >> 16) & 1u;
    x += 0x7fffu + lsb;                 // round-to-nearest-even
    return (unsigned short)(x >> 16);
}
__device__ __forceinline__ unsigned int pack2(float a, float b) {
    return (unsigned int)f2bfu(a) | ((unsigned int)f2bfu(b) << 16);
}
__device__ __forceinline__ float unpk_lo(unsigned int u) {
    return __builtin_bit_cast(float, u << 16);
}
__device__ __forceinline__ float unpk_hi(unsigned int u) {
    return __builtin_bit_cast(float, u & 0xffff0000u);
}

// ===========================================================================
// FAST PATH — 4 dispatches. NOTE (r11 lesson): do NOT fuse via device-wide
// barriers — gfx950 cross-XCD fence+atomic barriers cost ~400 µs each.
// ===========================================================================

// K0: weight transpose+convert. grid 32: mat = bx>>3, slab = bx&7.
__global__ __launch_bounds__(256) void prep_w(
    const float* __restrict__ Wq, const float* __restrict__ Wk,
    const float* __restrict__ Wv, const float* __restrict__ Wo,
    unsigned short* __restrict__ WqT, unsigned short* __restrict__ WkT,
    unsigned short* __restrict__ WvT, unsigned short* __restrict__ WoT) {
    int mat  = blockIdx.x >> 3;
    int slab = blockIdx.x & 7;
    const float* W = (mat == 0) ? Wq : (mat == 1) ? Wk : (mat == 2) ? Wv : Wo;
    unsigned short* WT = (mat == 0) ? WqT : (mat == 1) ? WkT : (mat == 2) ? WvT : WoT;
    int t = threadIdx.x;
    #pragma unroll
    for (int i = 0; i < 8; ++i) {
        int idx = t + 256 * i;
        int r = slab * 16 + (idx >> 7);
        int c = idx & 127;
        WT[c * 128 + r] = f2bfu(W[r * 128 + c]);
    }
}

// K1: four projections. grid (256, 4), 64 rows/block (4 blocks/CU):
//   y=0: EQb; y=1: EKV K-half; y=2: EKV V-half; y=3: RKb (237 rows).
__global__ __launch_bounds__(256) void gemm4_mfma(
    const float* __restrict__ entity, const float* __restrict__ rel_table,
    const unsigned short* __restrict__ WqT, const unsigned short* __restrict__ WkT,
    const unsigned short* __restrict__ WvT,
    const float* __restrict__ bq, const float* __restrict__ bk,
    const float* __restrict__ bv,
    unsigned short* __restrict__ EQb, unsigned short* __restrict__ EKV,
    unsigned short* __restrict__ RKb) {
    __shared__ __align__(16) unsigned short lw[128 * 136];

    int y = blockIdx.y;
    const float* A; const unsigned short* WT; const float* bias; int arows;
    unsigned short* outb; int ostride, ooff;
    if (y == 0)      { A = entity;    WT = WqT; bias = bq;      arows = M_NODES; outb = EQb; ostride = 128; ooff = 0;   }
    else if (y == 1) { A = entity;    WT = WkT; bias = nullptr; arows = M_NODES; outb = EKV; ostride = 256; ooff = 0;   }
    else if (y == 2) { A = entity;    WT = WvT; bias = bv;      arows = M_NODES; outb = EKV; ostride = 256; ooff = 128; }
    else             { A = rel_table; WT = WkT; bias = bk;      arows = RREL;    outb = RKb; ostride = 128; ooff = 0;   }

    int rbase = blockIdx.x * 64;
    if (rbase >= arows) return;
    int t = threadIdx.x;

    // stage WT into LDS (b128 copies), stride 136 bf16
    #pragma unroll
    for (int i = 0; i < 8; ++i) {
        int ci = t + 256 * i;
        int r  = ci >> 4;
        int c8 = ci & 15;
        *(short8*)&lw[r * 136 + c8 * 8] = *(const short8*)&WT[r * 128 + c8 * 8];
    }
    __syncthreads();

    int wave = t >> 6, lane = t & 63;
    int lm = lane & 15, quad = lane >> 4;
    int m0 = rbase + wave * 16;           // 16 rows per wave

    floatx4 acc[8];
    #pragma unroll
    for (int c = 0; c < 8; ++c) acc[c] = (floatx4){0.f, 0.f, 0.f, 0.f};

    int r0 = m0 + lm; if (r0 >= arows) r0 = arows - 1;

    #pragma unroll
    for (int ks = 0; ks < 4; ++ks) {
        int koff = ks * 32 + quad * 8;
        float4v f0 = *(const float4v*)&A[r0 * 128 + koff];
        float4v f1 = *(const float4v*)&A[r0 * 128 + koff + 4];
        short8 a;
        #pragma unroll
        for (int j = 0; j < 4; ++j) {
            a[j]     = (short)f2bfu(f0[j]);
            a[4 + j] = (short)f2bfu(f1[j]);
        }
        #pragma unroll
        for (int c = 0; c < 8; ++c) {
            short8 b = *(const short8*)&lw[(c * 16 + lm) * 136 + koff];
            acc[c] = __builtin_amdgcn_mfma_f32_16x16x32_bf16(a, b, acc[c], 0, 0, 0);
        }
    }

    #pragma unroll
    for (int c = 0; c < 8; ++c) {
        int col = c * 16 + lm;
        float bb = bias ? bias[col] : 0.0f;
        int rb = m0 + quad * 4;
        #pragma unroll
        for (int j = 0; j < 4; ++j) {
            int r = rb + j;
            if (r < arows) outb[r * ostride + ooff + col] = f2bfu(acc[c][j] + bb);
        }
    }
}

// K2: wave-per-node attention with V-row register prefetch (software pipeline:
// V-gather latency overlaps logit+softmax compute). grid 4096 x 256.
__global__ __launch_bounds__(256) void attn_gather(
    const int* __restrict__ nidx, const int* __restrict__ nrel,
    const int* __restrict__ nmask,
    const unsigned short* __restrict__ EQb, const unsigned short* __restrict__ EKV,
    const unsigned short* __restrict__ RKb,
    unsigned short* __restrict__ OATb) {
    __shared__ float Pl[4][8][33];
    __shared__ int mix[4][32];

    int w = threadIdx.x >> 6, l = threadIdx.x & 63;
    int m = blockIdx.x * 4 + w;
    int half = l >> 5, n = l & 31;
    int dgrp = l & 15, ngrp = l >> 4;
    int h2 = dgrp >> 1;

    int mk = nmask[m * NNBR + n];
    int ix = nidx[m * NNBR + n];
    int ir = nrel[m * NNBR + n];
    if (!mk) { ix = 0; ir = 0; }
    ix = ix < 0 ? 0 : (ix > M_NODES - 1 ? M_NODES - 1 : ix);
    ir = ir < 0 ? 0 : (ir > RREL - 1 ? RREL - 1 : ir);
    if (l < 32) mix[w][l] = ix;          // wave-private, same-wave in-order LDS

    // ---- V prefetch: issue all 8 V-row loads before the logit phase ----
    short8 vreg[8];
    #pragma unroll
    for (int i = 0; i < 8; ++i) {
        int ixx = mix[w][ngrp + i * 4];
        vreg[i] = *(const short8*)&EKV[ixx * 256 + 128 + dgrp * 8];
    }

    // ---- logits for heads half*4..+3 (dims half*64..+63) ----
    const unsigned short* qp = &EQb[m * 128 + half * 64];
    const unsigned short* kp = &EKV[ix * 256 + half * 64];
    const unsigned short* rp = &RKb[ir * 128 + half * 64];
    float acc[4] = {0.f, 0.f, 0.f, 0.f};
    #pragma unroll
    for (int c = 0; c < 8; ++c) {
        short8 q8 = *(const short8*)&qp[c * 8];
        short8 k8 = *(const short8*)&kp[c * 8];
        short8 r8 = *(const short8*)&rp[c * 8];
        int hh = c >> 1;
        #pragma unroll
        for (int j = 0; j < 8; ++j)
            acc[hh] += bfu2f((unsigned short)q8[j]) *
                       (bfu2f((unsigned short)k8[j]) + bfu2f((unsigned short)r8[j]));
    }
    #pragma unroll
    for (int hh = 0; hh < 4; ++hh) {
        float lf = acc[hh] * ATTN_SCALE;
        if (!mk) lf = -1e30f;
        float mx = lf;
        #pragma unroll
        for (int off = 16; off >= 1; off >>= 1) mx = fmaxf(mx, __shfl_xor(mx, off, 32));
        float p = __expf(lf - mx);
        float s = p;
        #pragma unroll
        for (int off = 16; off >= 1; off >>= 1) s += __shfl_xor(s, off, 32);
        Pl[w][half * 4 + hh][n] = p / s;
    }

    // ---- PV from prefetched registers ----
    float o[8] = {0.f, 0.f, 0.f, 0.f, 0.f, 0.f, 0.f, 0.f};
    #pragma unroll
    for (int i = 0; i < 8; ++i) {
        float pp = Pl[w][h2][ngrp + i * 4];
        #pragma unroll
        for (int j = 0; j < 8; ++j) o[j] += pp * bfu2f((unsigned short)vreg[i][j]);
    }
    #pragma unroll
    for (int j = 0; j < 8; ++j) {
        o[j] += __shfl_xor(o[j], 16, 64);
        o[j] += __shfl_xor(o[j], 32, 64);
    }
    if (ngrp == 0) {
        uint4v u;
        u[0] = pack2(o[0], o[1]); u[1] = pack2(o[2], o[3]);
        u[2] = pack2(o[4], o[5]); u[3] = pack2(o[6], o[7]);
        *(uint4v*)&OATb[m * 128 + dgrp * 8] = u;
    }
}

// K3: Y = OATb@Wo + bo + entity -> LayerNorm. grid 256, 128 thr.
__global__ __launch_bounds__(128) void gemm_wo_ln(
    const unsigned short* __restrict__ OATb, const unsigned short* __restrict__ WoT,
    const float* __restrict__ bo, const float* __restrict__ entity,
    const float* __restrict__ gamma_, const float* __restrict__ beta_,
    float* __restrict__ OUT) {
    __shared__ __align__(16) unsigned short lw[128 * 136];

    int t = threadIdx.x;
    #pragma unroll
    for (int i = 0; i < 16; ++i) {
        int ci = t + 128 * i;
        int r  = ci >> 4;
        int c8 = ci & 15;
        *(short8*)&lw[r * 136 + c8 * 8] = *(const short8*)&WoT[r * 128 + c8 * 8];
    }
    __syncthreads();

    int wave = t >> 6, lane = t & 63;
    int lm = lane & 15, quad = lane >> 4;
    int rbase = blockIdx.x * 64;
    int m0 = rbase + wave * 32;

    floatx4 acc[2][8];
    #pragma unroll
    for (int i = 0; i < 2; ++i)
        #pragma unroll
        for (int c = 0; c < 8; ++c) acc[i][c] = (floatx4){0.f, 0.f, 0.f, 0.f};

    int r0 = m0 + lm, r1 = m0 + 16 + lm;
    #pragma unroll
    for (int ks = 0; ks < 4; ++ks) {
        int koff = ks * 32 + quad * 8;
        short8 a0 = *(const short8*)&OATb[r0 * 128 + koff];
        short8 a1 = *(const short8*)&OATb[r1 * 128 + koff];
        #pragma unroll
        for (int c = 0; c < 8; ++c) {
            short8 b = *(const short8*)&lw[(c * 16 + lm) * 136 + koff];
            acc[0][c] = __builtin_amdgcn_mfma_f32_16x16x32_bf16(a0, b, acc[0][c], 0, 0, 0);
            acc[1][c] = __builtin_amdgcn_mfma_f32_16x16x32_bf16(a1, b, acc[1][c], 0, 0, 0);
        }
    }

    float bb[8], gg[8], be[8];
    #pragma unroll
    for (int c = 0; c < 8; ++c) {
        int col = c * 16 + lm;
        bb[c] = bo[col]; gg[c] = gamma_[col]; be[c] = beta_[col];
    }
    #pragma unroll
    for (int i = 0; i < 2; ++i) {
        #pragma unroll
        for (int j = 0; j < 4; ++j) {
            int r = m0 + i * 16 + quad * 4 + j;
            float y[8];
            float s1 = 0.f, s2 = 0.f;
            #pragma unroll
            for (int c = 0; c < 8; ++c) {
                float v = acc[i][c][j] + bb[c] + entity[r * 128 + c * 16 + lm];
                y[c] = v; s1 += v; s2 += v * v;
            }
            #pragma unroll
            for (int off = 8; off >= 1; off >>= 1) {
                s1 += __shfl_xor(s1, off, 16);
                s2 += __shfl_xor(s2, off, 16);
            }
            float mu  = s1 * (1.0f / 128.0f);
            float var = fmaxf(s2 * (1.0f / 128.0f) - mu * mu, 0.0f);
            float rs  = rsqrtf(var + LN_EPS);
            #pragma unroll
            for (int c = 0; c < 8; ++c)
                OUT[r * 128 + c * 16 + lm] = (y[c] - mu) * rs * gg[c] + be[c];
        }
    }
}

// ===========================================================================
// FALLBACK (round-5 fused kernel, ~314 µs) — used if ws too small
// ===========================================================================
__global__ __launch_bounds__(256, 6) void rga_fused(
    const float* __restrict__ entity,
    const int* __restrict__ nidx,
    const int* __restrict__ nrel,
    const int* __restrict__ nmask,
    const float* __restrict__ Wq, const float* __restrict__ bq,
    const float* __restrict__ Wk, const float* __restrict__ bk,
    const float* __restrict__ Wv, const float* __restrict__ bv,
    const float* __restrict__ Wo, const float* __restrict__ bo,
    const float* __restrict__ rel_table,
    const float* __restrict__ gamma_, const float* __restrict__ beta_,
    float* __restrict__ outp) {
    __shared__ __align__(16) float er[128];
    __shared__ __align__(16) float qv[128];
    __shared__ float qb[8];
    __shared__ __align__(16) float qk[8 * 132];
    __shared__ __align__(16) unsigned int nbvp[32 * 68];
    __shared__ float Lg[8][33];
    __shared__ __align__(16) float pv[8 * 132];
    __shared__ __align__(16) float oat[128];
    __shared__ float ypart[2][128];
    __shared__ float red[4];
    __shared__ int midx[32], mrel[32], mmask[32];

    int m = blockIdx.x;
    int t = threadIdx.x;

    if (t < 32) {
        int mk = nmask[m * NNBR + t];
        int ix = nidx[m * NNBR + t];
        int ir = nrel[m * NNBR + t];
        if (!mk) { ix = 0; ir = 0; }
        ix = ix < 0 ? 0 : (ix > M_NODES - 1 ? M_NODES - 1 : ix);
        ir = ir < 0 ? 0 : (ir > RREL - 1 ? RREL - 1 : ir);
        mmask[t] = mk; midx[t] = ix; mrel[t] = ir;
    }
    if (t >= 128) er[t - 128] = entity[m * 128 + (t - 128)];
    __syncthreads();

    {
        int half = t >> 7, d = t & 127, j0 = half * 64;
        const float4v* e4 = (const float4v*)&er[j0];
        float acc = 0.f;
        #pragma unroll 4
        for (int c = 0; c < 16; ++c) {
            float4v ev = e4[c];
            #pragma unroll
            for (int k = 0; k < 4; ++k)
                acc += ev[k] * Wq[(j0 + c * 4 + k) * 128 + d];
        }
        ypart[half][d] = acc;
    }
    __syncthreads();
    if (t < 128) qv[t] = ypart[0][t] + ypart[1][t] + bq[t];
    __syncthreads();

    #pragma unroll
    for (int rep = 0; rep < 4; ++rep) {
        int o = rep * 256 + t;
        int h = o >> 7, j = o & 127;
        const float4v* wr = (const float4v*)&Wk[j * 128 + h * 16];
        const float4v* q4 = (const float4v*)&qv[h * 16];
        float s = 0.f;
        #pragma unroll
        for (int c = 0; c < 4; ++c) {
            float4v ww = wr[c], q = q4[c];
            #pragma unroll
            for (int k = 0; k < 4; ++k) s += ww[k] * q[k];
        }
        qk[h * 132 + j] = s;
    }
    if (t < 8) {
        float s = 0.f;
        #pragma unroll
        for (int dh = 0; dh < 16; ++dh) s += qv[t * 16 + dh] * bk[t * 16 + dh];
        qb[t] = s;
    }
    __syncthreads();

    {
        int n = t >> 3, c16 = t & 7, j0 = c16 * 16;
        int ix = midx[n], ir = mrel[n];
        const float4v* ep = (const float4v*)&entity[ix * 128 + j0];
        const float4v* rp = (const float4v*)&rel_table[ir * 128 + j0];
        float ev[16], kv[16];
        #pragma unroll
        for (int c = 0; c < 4; ++c) {
            float4v e4 = ep[c], r4 = rp[c];
            #pragma unroll
            for (int k = 0; k < 4; ++k) {
                ev[c * 4 + k] = e4[k];
                kv[c * 4 + k] = e4[k] + r4[k];
            }
        }
        uint4v u0, u1;
        #pragma unroll
        for (int k = 0; k < 4; ++k) u0[k] = pack2(ev[2 * k], ev[2 * k + 1]);
        #pragma unroll
        for (int k = 0; k < 4; ++k) u1[k] = pack2(ev[8 + 2 * k], ev[9 + 2 * k]);
        *(uint4v*)&nbvp[n * 68 + c16 * 8]     = u0;
        *(uint4v*)&nbvp[n * 68 + c16 * 8 + 4] = u1;
        float acc[8];
        #pragma unroll
        for (int h = 0; h < 8; ++h) {
            const float4v* qrow = (const float4v*)&qk[h * 132 + j0];
            float s = 0.f;
            #pragma unroll
            for (int c = 0; c < 4; ++c) {
                float4v q = qrow[c];
                #pragma unroll
                for (int k = 0; k < 4; ++k) s += q[k] * kv[c * 4 + k];
            }
            acc[h] = s;
        }
        #pragma unroll
        for (int off = 1; off < 8; off <<= 1) {
            #pragma unroll
            for (int h = 0; h < 8; ++h) acc[h] += __shfl_xor(acc[h], off, 8);
        }
        if (c16 == 0) {
            #pragma unroll
            for (int h = 0; h < 8; ++h) {
                float lf = (acc[h] + qb[h]) * ATTN_SCALE;
                if (!mmask[n]) lf = -1e30f;
                Lg[h][n] = lf;
            }
        }
    }
    __syncthreads();

    {
        int h = t >> 5, n = t & 31;
        float lf = Lg[h][n];
        float mx = lf;
        #pragma unroll
        for (int off = 16; off >= 1; off >>= 1) mx = fmaxf(mx, __shfl_xor(mx, off, 32));
        float p = __expf(lf - mx);
        float s = p;
        #pragma unroll
        for (int off = 16; off >= 1; off >>= 1) s += __shfl_xor(s, off, 32);
        Lg[h][n] = p / s;
    }
    __syncthreads();

    {
        int h = t >> 5, c4 = t & 31;
        float4v a = (float4v){0.f, 0.f, 0.f, 0.f};
        #pragma unroll 8
        for (int n = 0; n < 32; ++n) {
            float p = Lg[h][n];
            unsigned int w0 = nbvp[n * 68 + c4 * 2];
            unsigned int w1 = nbvp[n * 68 + c4 * 2 + 1];
            a[0] += p * unpk_lo(w0);
            a[1] += p * unpk_hi(w0);
            a[2] += p * unpk_lo(w1);
            a[3] += p * unpk_hi(w1);
        }
        *(float4v*)&pv[h * 132 + c4 * 4] = a;
    }
    __syncthreads();

    {
        int half = t >> 7, d = t & 127, j0 = half * 64;
        int h = d >> 4;
        const float4v* p4 = (const float4v*)&pv[h * 132 + j0];
        float acc = 0.f;
        #pragma unroll 4
        for (int c = 0; c < 16; ++c) {
            float4v p = p4[c];
            #pragma unroll
            for (int k = 0; k < 4; ++k)
                acc += p[k] * Wv[(j0 + c * 4 + k) * 128 + d];
        }
        ypart[half][d] = acc;
    }
    __syncthreads();
    if (t < 128) oat[t] = ypart[0][t] + ypart[1][t] + bv[t];
    __syncthreads();

    {
        int half = t >> 7, d = t & 127, j0 = half * 64;
        const float4v* o4 = (const float4v*)&oat[j0];
        float acc = 0.f;
        #pragma unroll 4
        for (int c = 0; c < 16; ++c) {
            float4v o = o4[c];
            #pragma unroll
            for (int k = 0; k < 4; ++k)
                acc += o[k] * Wo[(j0 + c * 4 + k) * 128 + d];
        }
        ypart[half][d] = acc;
    }
    __syncthreads();

    float x = 0.f;
    if (t < 128) {
        x = er[t] + ypart[0][t] + ypart[1][t] + bo[t];
        float s1 = x, s2 = x * x;
        #pragma unroll
        for (int off = 32; off >= 1; off >>= 1) {
            s1 += __shfl_xor(s1, off, 64);
            s2 += __shfl_xor(s2, off, 64);
        }
        if ((t & 63) == 0) { red[(t >> 6) * 2] = s1; red[(t >> 6) * 2 + 1] = s2; }
    }
    __syncthreads();
    if (t < 128) {
        float mu  = (red[0] + red[2]) * (1.0f / 128.0f);
        float ms  = (red[1] + red[3]) * (1.0f / 128.0f);
        float var = fmaxf(ms - mu * mu, 0.0f);
        float rs  = rsqrtf(var + LN_EPS);
        outp[m * 128 + t] = (x - mu) * rs * gamma_[t] + beta_[t];
    }
}

// ---------------------------------------------------------------------------
extern "C" void kernel_launch(void* const* d_in, const int* in_sizes, int n_in,
                              void* d_out, int out_size, void* d_ws, size_t ws_size,
                              hipStream_t stream) {
    const float* entity    = (const float*)d_in[0];
    const int*   nidx      = (const int*)d_in[1];
    const int*   nrel      = (const int*)d_in[2];
    const int*   nmask     = (const int*)d_in[3];
    const float* Wq        = (const float*)d_in[4];
    const float* bq        = (const float*)d_in[5];
    const float* Wk        = (const float*)d_in[6];
    const float* bk        = (const float*)d_in[7];
    const float* Wv        = (const float*)d_in[8];
    const float* bv        = (const float*)d_in[9];
    const float* Wo        = (const float*)d_in[10];
    const float* bo        = (const float*)d_in[11];
    const float* rel_table = (const float*)d_in[12];
    const float* gamma_    = (const float*)d_in[13];
    const float* beta_     = (const float*)d_in[14];

    // ws layout:
    //   EKV (bf16) 8M     @ 0
    //   EQb (bf16) 4M     @ 8388608
    //   OATb(bf16) 4M     @ 12582912
    //   RKb (bf16) 60672  @ 16777216
    //   WqT/WkT/WvT/WoT 32K each @ 16837888
    char* ws = (char*)d_ws;
    unsigned short* EKV  = (unsigned short*)(ws + 0);
    unsigned short* EQb  = (unsigned short*)(ws + 8388608);
    unsigned short* OATb = (unsigned short*)(ws + 12582912);
    unsigned short* RKb  = (unsigned short*)(ws + 16777216);
    unsigned short* WqT  = (unsigned short*)(ws + 16837888);
    unsigned short* WkT  = (unsigned short*)(ws + 16870656);
    unsigned short* WvT  = (unsigned short*)(ws + 16903424);
    unsigned short* WoT  = (unsigned short*)(ws + 16936192);
    const size_t NEED = 16968960;

    if (ws_size >= NEED) {
        prep_w<<<dim3(32), 256, 0, stream>>>(Wq, Wk, Wv, Wo, WqT, WkT, WvT, WoT);
        gemm4_mfma<<<dim3(256, 4), 256, 0, stream>>>(
            entity, rel_table, WqT, WkT, WvT, bq, bk, bv, EQb, EKV, RKb);
        attn_gather<<<dim3(M_NODES / 4), 256, 0, stream>>>(
            nidx, nrel, nmask, EQb, EKV, RKb, OATb);
        gemm_wo_ln<<<dim3(256), 128, 0, stream>>>(
            OATb, WoT, bo, entity, gamma_, beta_, (float*)d_out);
    } else {
        rga_fused<<<dim3(M_NODES), 256, 0, stream>>>(
            entity, nidx, nrel, nmask, Wq, bq, Wk, bk, Wv, bv, Wo, bo,
            rel_table, gamma_, beta_, (float*)d_out);
    }
}

// Round 13
// 145.370 us; speedup vs baseline: 9.1860x; 1.0771x over previous
//
#include <hip/hip_runtime.h>

#define M_NODES 16384
#define NNBR 32
#define RREL 237
#define ATTN_SCALE 0.25f   // (128/8)^-0.5
#define LN_EPS 1e-5f

typedef float float4v __attribute__((ext_vector_type(4)));
typedef unsigned int uint4v __attribute__((ext_vector_type(4)));
typedef short short8 __attribute__((ext_vector_type(8)));
typedef float floatx4 __attribute__((ext_vector_type(4)));

__device__ __forceinline__ float bfu2f(unsigned short u) {
    return __builtin_bit_cast(float, ((unsigned int)u) << 16);
}
__device__ __forceinline__ unsigned short f2bfu(float f) {
    unsigned int x = __builtin_bit_cast(unsigned int, f);
    unsigned int lsb = (x >> 16) & 1u;
    x += 0x7fffu + lsb;                 // round-to-nearest-even
    return (unsigned short)(x >> 16);
}
__device__ __forceinline__ unsigned int pack2(float a, float b) {
    return (unsigned int)f2bfu(a) | ((unsigned int)f2bfu(b) << 16);
}
__device__ __forceinline__ float unpk_lo(unsigned int u) {
    return __builtin_bit_cast(float, u << 16);
}
__device__ __forceinline__ float unpk_hi(unsigned int u) {
    return __builtin_bit_cast(float, u & 0xffff0000u);
}

// ===========================================================================
// FAST PATH — 4 dispatches. Cost model (r12): wall = ~40 fixed + ~46 ws-fill
// + sum(kernels); per-dispatch cost ~0. r11 lesson: never use device barriers.
// ===========================================================================

// K0: weight transpose+convert. grid 32: mat = bx>>3, slab = bx&7.
__global__ __launch_bounds__(256) void prep_w(
    const float* __restrict__ Wq, const float* __restrict__ Wk,
    const float* __restrict__ Wv, const float* __restrict__ Wo,
    unsigned short* __restrict__ WqT, unsigned short* __restrict__ WkT,
    unsigned short* __restrict__ WvT, unsigned short* __restrict__ WoT) {
    int mat  = blockIdx.x >> 3;
    int slab = blockIdx.x & 7;
    const float* W = (mat == 0) ? Wq : (mat == 1) ? Wk : (mat == 2) ? Wv : Wo;
    unsigned short* WT = (mat == 0) ? WqT : (mat == 1) ? WkT : (mat == 2) ? WvT : WoT;
    int t = threadIdx.x;
    #pragma unroll
    for (int i = 0; i < 8; ++i) {
        int idx = t + 256 * i;
        int r = slab * 16 + (idx >> 7);
        int c = idx & 127;
        WT[c * 128 + r] = f2bfu(W[r * 128 + c]);
    }
}

// K1: four projections. grid (256, 4), 64 rows/block:
//   y=0: EQb; y=1: EKV K-half; y=2: EKV V-half; y=3: RKb (237 rows).
__global__ __launch_bounds__(256) void gemm4_mfma(
    const float* __restrict__ entity, const float* __restrict__ rel_table,
    const unsigned short* __restrict__ WqT, const unsigned short* __restrict__ WkT,
    const unsigned short* __restrict__ WvT,
    const float* __restrict__ bq, const float* __restrict__ bk,
    const float* __restrict__ bv,
    unsigned short* __restrict__ EQb, unsigned short* __restrict__ EKV,
    unsigned short* __restrict__ RKb) {
    __shared__ __align__(16) unsigned short lw[128 * 136];

    int y = blockIdx.y;
    const float* A; const unsigned short* WT; const float* bias; int arows;
    unsigned short* outb; int ostride, ooff;
    if (y == 0)      { A = entity;    WT = WqT; bias = bq;      arows = M_NODES; outb = EQb; ostride = 128; ooff = 0;   }
    else if (y == 1) { A = entity;    WT = WkT; bias = nullptr; arows = M_NODES; outb = EKV; ostride = 256; ooff = 0;   }
    else if (y == 2) { A = entity;    WT = WvT; bias = bv;      arows = M_NODES; outb = EKV; ostride = 256; ooff = 128; }
    else             { A = rel_table; WT = WkT; bias = bk;      arows = RREL;    outb = RKb; ostride = 128; ooff = 0;   }

    int rbase = blockIdx.x * 64;
    if (rbase >= arows) return;
    int t = threadIdx.x;

    #pragma unroll
    for (int i = 0; i < 8; ++i) {
        int ci = t + 256 * i;
        int r  = ci >> 4;
        int c8 = ci & 15;
        *(short8*)&lw[r * 136 + c8 * 8] = *(const short8*)&WT[r * 128 + c8 * 8];
    }
    __syncthreads();

    int wave = t >> 6, lane = t & 63;
    int lm = lane & 15, quad = lane >> 4;
    int m0 = rbase + wave * 16;

    floatx4 acc[8];
    #pragma unroll
    for (int c = 0; c < 8; ++c) acc[c] = (floatx4){0.f, 0.f, 0.f, 0.f};

    int r0 = m0 + lm; if (r0 >= arows) r0 = arows - 1;

    #pragma unroll
    for (int ks = 0; ks < 4; ++ks) {
        int koff = ks * 32 + quad * 8;
        float4v f0 = *(const float4v*)&A[r0 * 128 + koff];
        float4v f1 = *(const float4v*)&A[r0 * 128 + koff + 4];
        short8 a;
        #pragma unroll
        for (int j = 0; j < 4; ++j) {
            a[j]     = (short)f2bfu(f0[j]);
            a[4 + j] = (short)f2bfu(f1[j]);
        }
        #pragma unroll
        for (int c = 0; c < 8; ++c) {
            short8 b = *(const short8*)&lw[(c * 16 + lm) * 136 + koff];
            acc[c] = __builtin_amdgcn_mfma_f32_16x16x32_bf16(a, b, acc[c], 0, 0, 0);
        }
    }

    #pragma unroll
    for (int c = 0; c < 8; ++c) {
        int col = c * 16 + lm;
        float bb = bias ? bias[col] : 0.0f;
        int rb = m0 + quad * 4;
        #pragma unroll
        for (int j = 0; j < 4; ++j) {
            int r = rb + j;
            if (r < arows) outb[r * ostride + ooff + col] = f2bfu(acc[c][j] + bb);
        }
    }
}

// K2: wave-per-node attention, MFMA logits. grid 4096 x 256 (4 nodes/block).
// logit[n][h] = K_rows @ Bq + R_rows @ Bq (chained MFMA, fp32 accum), where
// Bq[k][h] = q[k]*delta(head(k)==h); head(k) is constant per (ks,quad) frag.
// C-layout: lane (lm,quad) holds logits for head=lm, n = g*16 + quad*4 + j.
__global__ __launch_bounds__(256) void attn_gather(
    const int* __restrict__ nidx, const int* __restrict__ nrel,
    const int* __restrict__ nmask,
    const unsigned short* __restrict__ EQb, const unsigned short* __restrict__ EKV,
    const unsigned short* __restrict__ RKb,
    unsigned short* __restrict__ OATb) {
    __shared__ float Pl[4][8][33];
    __shared__ int mix[4][32];
    __shared__ int mrl[4][32];

    int w = threadIdx.x >> 6, l = threadIdx.x & 63;
    int m = blockIdx.x * 4 + w;
    int lm = l & 15, quad = l >> 4;
    int n0 = l & 31;

    int mk = nmask[m * NNBR + n0];
    int ix = nidx[m * NNBR + n0];
    int ir = nrel[m * NNBR + n0];
    if (!mk) { ix = 0; ir = 0; }
    ix = ix < 0 ? 0 : (ix > M_NODES - 1 ? M_NODES - 1 : ix);
    ir = ir < 0 ? 0 : (ir > RREL - 1 ? RREL - 1 : ir);
    unsigned long long bal = __ballot(mk != 0);
    unsigned maskbits = (unsigned)(bal & 0xffffffffu);   // bit n = mask of nbr n
    if (l < 32) { mix[w][l] = ix; mrl[w][l] = ir; }      // wave-private LDS

    // ---- V prefetch (PV mapping: dgrp=lm owns dims lm*8..+7, ngrp=quad) ----
    short8 vreg[8];
    #pragma unroll
    for (int i = 0; i < 8; ++i) {
        int ixx = mix[w][quad + i * 4];
        vreg[i] = *(const short8*)&EKV[ixx * 256 + 128 + lm * 8];
    }

    // ---- MFMA logits: A = K/R rows (row=mix[g*16+lm], k=ks*32+quad*8) ----
    int rowK0 = mix[w][lm],      rowK1 = mix[w][16 + lm];
    int rowR0 = mrl[w][lm],      rowR1 = mrl[w][16 + lm];

    floatx4 acc0 = (floatx4){0.f, 0.f, 0.f, 0.f};
    floatx4 acc1 = (floatx4){0.f, 0.f, 0.f, 0.f};
    const short8 zero8 = (short8){0, 0, 0, 0, 0, 0, 0, 0};
    #pragma unroll
    for (int ks = 0; ks < 4; ++ks) {
        int koff = ks * 32 + quad * 8;
        short8 q8 = *(const short8*)&EQb[m * 128 + koff];
        int h = ks * 2 + (quad >> 1);             // head of this k-fragment
        short8 bq = (lm == h) ? q8 : zero8;       // Bq[k][col=lm]
        short8 k0 = *(const short8*)&EKV[rowK0 * 256 + koff];
        short8 k1 = *(const short8*)&EKV[rowK1 * 256 + koff];
        short8 r0 = *(const short8*)&RKb[rowR0 * 128 + koff];
        short8 r1 = *(const short8*)&RKb[rowR1 * 128 + koff];
        acc0 = __builtin_amdgcn_mfma_f32_16x16x32_bf16(k0, bq, acc0, 0, 0, 0);
        acc0 = __builtin_amdgcn_mfma_f32_16x16x32_bf16(r0, bq, acc0, 0, 0, 0);
        acc1 = __builtin_amdgcn_mfma_f32_16x16x32_bf16(k1, bq, acc1, 0, 0, 0);
        acc1 = __builtin_amdgcn_mfma_f32_16x16x32_bf16(r1, bq, acc1, 0, 0, 0);
    }

    // ---- masked softmax in C-layout (head = lm, n = g*16 + quad*4 + j) ----
    float lf[2][4];
    #pragma unroll
    for (int j = 0; j < 4; ++j) {
        int na = quad * 4 + j, nb = 16 + quad * 4 + j;
        float va = acc0[j] * ATTN_SCALE;
        float vb = acc1[j] * ATTN_SCALE;
        lf[0][j] = ((maskbits >> na) & 1) ? va : -1e30f;
        lf[1][j] = ((maskbits >> nb) & 1) ? vb : -1e30f;
    }
    float mx = -1e30f;
    #pragma unroll
    for (int g = 0; g < 2; ++g)
        #pragma unroll
        for (int j = 0; j < 4; ++j) mx = fmaxf(mx, lf[g][j]);
    mx = fmaxf(mx, __shfl_xor(mx, 16, 64));
    mx = fmaxf(mx, __shfl_xor(mx, 32, 64));
    float p[2][4];
    float s = 0.f;
    #pragma unroll
    for (int g = 0; g < 2; ++g)
        #pragma unroll
        for (int j = 0; j < 4; ++j) { p[g][j] = __expf(lf[g][j] - mx); s += p[g][j]; }
    s += __shfl_xor(s, 16, 64);
    s += __shfl_xor(s, 32, 64);
    float inv = 1.0f / s;
    if (lm < 8) {
        #pragma unroll
        for (int g = 0; g < 2; ++g)
            #pragma unroll
            for (int j = 0; j < 4; ++j)
                Pl[w][lm][g * 16 + quad * 4 + j] = p[g][j] * inv;
    }

    // ---- PV from prefetched registers (same-wave LDS, no barrier) ----
    float o[8] = {0.f, 0.f, 0.f, 0.f, 0.f, 0.f, 0.f, 0.f};
    #pragma unroll
    for (int i = 0; i < 8; ++i) {
        float pp = Pl[w][lm >> 1][quad + i * 4];
        #pragma unroll
        for (int j = 0; j < 8; ++j) o[j] += pp * bfu2f((unsigned short)vreg[i][j]);
    }
    #pragma unroll
    for (int j = 0; j < 8; ++j) {
        o[j] += __shfl_xor(o[j], 16, 64);
        o[j] += __shfl_xor(o[j], 32, 64);
    }
    if (quad == 0) {
        uint4v u;
        u[0] = pack2(o[0], o[1]); u[1] = pack2(o[2], o[3]);
        u[2] = pack2(o[4], o[5]); u[3] = pack2(o[6], o[7]);
        *(uint4v*)&OATb[m * 128 + lm * 8] = u;
    }
}

// K3: Y = OATb@Wo + bo + entity -> LayerNorm. grid 256, 128 thr.
__global__ __launch_bounds__(128) void gemm_wo_ln(
    const unsigned short* __restrict__ OATb, const unsigned short* __restrict__ WoT,
    const float* __restrict__ bo, const float* __restrict__ entity,
    const float* __restrict__ gamma_, const float* __restrict__ beta_,
    float* __restrict__ OUT) {
    __shared__ __align__(16) unsigned short lw[128 * 136];

    int t = threadIdx.x;
    #pragma unroll
    for (int i = 0; i < 16; ++i) {
        int ci = t + 128 * i;
        int r  = ci >> 4;
        int c8 = ci & 15;
        *(short8*)&lw[r * 136 + c8 * 8] = *(const short8*)&WoT[r * 128 + c8 * 8];
    }
    __syncthreads();

    int wave = t >> 6, lane = t & 63;
    int lm = lane & 15, quad = lane >> 4;
    int rbase = blockIdx.x * 64;
    int m0 = rbase + wave * 32;

    floatx4 acc[2][8];
    #pragma unroll
    for (int i = 0; i < 2; ++i)
        #pragma unroll
        for (int c = 0; c < 8; ++c) acc[i][c] = (floatx4){0.f, 0.f, 0.f, 0.f};

    int r0 = m0 + lm, r1 = m0 + 16 + lm;
    #pragma unroll
    for (int ks = 0; ks < 4; ++ks) {
        int koff = ks * 32 + quad * 8;
        short8 a0 = *(const short8*)&OATb[r0 * 128 + koff];
        short8 a1 = *(const short8*)&OATb[r1 * 128 + koff];
        #pragma unroll
        for (int c = 0; c < 8; ++c) {
            short8 b = *(const short8*)&lw[(c * 16 + lm) * 136 + koff];
            acc[0][c] = __builtin_amdgcn_mfma_f32_16x16x32_bf16(a0, b, acc[0][c], 0, 0, 0);
            acc[1][c] = __builtin_amdgcn_mfma_f32_16x16x32_bf16(a1, b, acc[1][c], 0, 0, 0);
        }
    }

    float bb[8], gg[8], be[8];
    #pragma unroll
    for (int c = 0; c < 8; ++c) {
        int col = c * 16 + lm;
        bb[c] = bo[col]; gg[c] = gamma_[col]; be[c] = beta_[col];
    }
    #pragma unroll
    for (int i = 0; i < 2; ++i) {
        #pragma unroll
        for (int j = 0; j < 4; ++j) {
            int r = m0 + i * 16 + quad * 4 + j;
            float y[8];
            float s1 = 0.f, s2 = 0.f;
            #pragma unroll
            for (int c = 0; c < 8; ++c) {
                float v = acc[i][c][j] + bb[c] + entity[r * 128 + c * 16 + lm];
                y[c] = v; s1 += v; s2 += v * v;
            }
            #pragma unroll
            for (int off = 8; off >= 1; off >>= 1) {
                s1 += __shfl_xor(s1, off, 16);
                s2 += __shfl_xor(s2, off, 16);
            }
            float mu  = s1 * (1.0f / 128.0f);
            float var = fmaxf(s2 * (1.0f / 128.0f) - mu * mu, 0.0f);
            float rs  = rsqrtf(var + LN_EPS);
            #pragma unroll
            for (int c = 0; c < 8; ++c)
                OUT[r * 128 + c * 16 + lm] = (y[c] - mu) * rs * gg[c] + be[c];
        }
    }
}

// ===========================================================================
// FALLBACK (round-5 fused kernel, ~314 µs) — used if ws too small
// ===========================================================================
__global__ __launch_bounds__(256, 6) void rga_fused(
    const float* __restrict__ entity,
    const int* __restrict__ nidx,
    const int* __restrict__ nrel,
    const int* __restrict__ nmask,
    const float* __restrict__ Wq, const float* __restrict__ bq,
    const float* __restrict__ Wk, const float* __restrict__ bk,
    const float* __restrict__ Wv, const float* __restrict__ bv,
    const float* __restrict__ Wo, const float* __restrict__ bo,
    const float* __restrict__ rel_table,
    const float* __restrict__ gamma_, const float* __restrict__ beta_,
    float* __restrict__ outp) {
    __shared__ __align__(16) float er[128];
    __shared__ __align__(16) float qv[128];
    __shared__ float qb[8];
    __shared__ __align__(16) float qk[8 * 132];
    __shared__ __align__(16) unsigned int nbvp[32 * 68];
    __shared__ float Lg[8][33];
    __shared__ __align__(16) float pv[8 * 132];
    __shared__ __align__(16) float oat[128];
    __shared__ float ypart[2][128];
    __shared__ float red[4];
    __shared__ int midx[32], mrel[32], mmask[32];

    int m = blockIdx.x;
    int t = threadIdx.x;

    if (t < 32) {
        int mk = nmask[m * NNBR + t];
        int ix = nidx[m * NNBR + t];
        int ir = nrel[m * NNBR + t];
        if (!mk) { ix = 0; ir = 0; }
        ix = ix < 0 ? 0 : (ix > M_NODES - 1 ? M_NODES - 1 : ix);
        ir = ir < 0 ? 0 : (ir > RREL - 1 ? RREL - 1 : ir);
        mmask[t] = mk; midx[t] = ix; mrel[t] = ir;
    }
    if (t >= 128) er[t - 128] = entity[m * 128 + (t - 128)];
    __syncthreads();

    {
        int half = t >> 7, d = t & 127, j0 = half * 64;
        const float4v* e4 = (const float4v*)&er[j0];
        float acc = 0.f;
        #pragma unroll 4
        for (int c = 0; c < 16; ++c) {
            float4v ev = e4[c];
            #pragma unroll
            for (int k = 0; k < 4; ++k)
                acc += ev[k] * Wq[(j0 + c * 4 + k) * 128 + d];
        }
        ypart[half][d] = acc;
    }
    __syncthreads();
    if (t < 128) qv[t] = ypart[0][t] + ypart[1][t] + bq[t];
    __syncthreads();

    #pragma unroll
    for (int rep = 0; rep < 4; ++rep) {
        int o = rep * 256 + t;
        int h = o >> 7, j = o & 127;
        const float4v* wr = (const float4v*)&Wk[j * 128 + h * 16];
        const float4v* q4 = (const float4v*)&qv[h * 16];
        float s = 0.f;
        #pragma unroll
        for (int c = 0; c < 4; ++c) {
            float4v ww = wr[c], q = q4[c];
            #pragma unroll
            for (int k = 0; k < 4; ++k) s += ww[k] * q[k];
        }
        qk[h * 132 + j] = s;
    }
    if (t < 8) {
        float s = 0.f;
        #pragma unroll
        for (int dh = 0; dh < 16; ++dh) s += qv[t * 16 + dh] * bk[t * 16 + dh];
        qb[t] = s;
    }
    __syncthreads();

    {
        int n = t >> 3, c16 = t & 7, j0 = c16 * 16;
        int ix = midx[n], ir = mrel[n];
        const float4v* ep = (const float4v*)&entity[ix * 128 + j0];
        const float4v* rp = (const float4v*)&rel_table[ir * 128 + j0];
        float ev[16], kv[16];
        #pragma unroll
        for (int c = 0; c < 4; ++c) {
            float4v e4 = ep[c], r4 = rp[c];
            #pragma unroll
            for (int k = 0; k < 4; ++k) {
                ev[c * 4 + k] = e4[k];
                kv[c * 4 + k] = e4[k] + r4[k];
            }
        }
        uint4v u0, u1;
        #pragma unroll
        for (int k = 0; k < 4; ++k) u0[k] = pack2(ev[2 * k], ev[2 * k + 1]);
        #pragma unroll
        for (int k = 0; k < 4; ++k) u1[k] = pack2(ev[8 + 2 * k], ev[9 + 2 * k]);
        *(uint4v*)&nbvp[n * 68 + c16 * 8]     = u0;
        *(uint4v*)&nbvp[n * 68 + c16 * 8 + 4] = u1;
        float acc[8];
        #pragma unroll
        for (int h = 0; h < 8; ++h) {
            const float4v* qrow = (const float4v*)&qk[h * 132 + j0];
            float s = 0.f;
            #pragma unroll
            for (int c = 0; c < 4; ++c) {
                float4v q = qrow[c];
                #pragma unroll
                for (int k = 0; k < 4; ++k) s += q[k] * kv[c * 4 + k];
            }
            acc[h] = s;
        }
        #pragma unroll
        for (int off = 1; off < 8; off <<= 1) {
            #pragma unroll
            for (int h = 0; h < 8; ++h) acc[h] += __shfl_xor(acc[h], off, 8);
        }
        if (c16 == 0) {
            #pragma unroll
            for (int h = 0; h < 8; ++h) {
                float lf = (acc[h] + qb[h]) * ATTN_SCALE;
                if (!mmask[n]) lf = -1e30f;
                Lg[h][n] = lf;
            }
        }
    }
    __syncthreads();

    {
        int h = t >> 5, n = t & 31;
        float lf = Lg[h][n];
        float mx = lf;
        #pragma unroll
        for (int off = 16; off >= 1; off >>= 1) mx = fmaxf(mx, __shfl_xor(mx, off, 32));
        float p = __expf(lf - mx);
        float s = p;
        #pragma unroll
        for (int off = 16; off >= 1; off >>= 1) s += __shfl_xor(s, off, 32);
        Lg[h][n] = p / s;
    }
    __syncthreads();

    {
        int h = t >> 5, c4 = t & 31;
        float4v a = (float4v){0.f, 0.f, 0.f, 0.f};
        #pragma unroll 8
        for (int n = 0; n < 32; ++n) {
            float p = Lg[h][n];
            unsigned int w0 = nbvp[n * 68 + c4 * 2];
            unsigned int w1 = nbvp[n * 68 + c4 * 2 + 1];
            a[0] += p * unpk_lo(w0);
            a[1] += p * unpk_hi(w0);
            a[2] += p * unpk_lo(w1);
            a[3] += p * unpk_hi(w1);
        }
        *(float4v*)&pv[h * 132 + c4 * 4] = a;
    }
    __syncthreads();

    {
        int half = t >> 7, d = t & 127, j0 = half * 64;
        int h = d >> 4;
        const float4v* p4 = (const float4v*)&pv[h * 132 + j0];
        float acc = 0.f;
        #pragma unroll 4
        for (int c = 0; c < 16; ++c) {
            float4v p = p4[c];
            #pragma unroll
            for (int k = 0; k < 4; ++k)
                acc += p[k] * Wv[(j0 + c * 4 + k) * 128 + d];
        }
        ypart[half][d] = acc;
    }
    __syncthreads();
    if (t < 128) oat[t] = ypart[0][t] + ypart[1][t] + bv[t];
    __syncthreads();

    {
        int half = t >> 7, d = t & 127, j0 = half * 64;
        const float4v* o4 = (const float4v*)&oat[j0];
        float acc = 0.f;
        #pragma unroll 4
        for (int c = 0; c < 16; ++c) {
            float4v o = o4[c];
            #pragma unroll
            for (int k = 0; k < 4; ++k)
                acc += o[k] * Wo[(j0 + c * 4 + k) * 128 + d];
        }
        ypart[half][d] = acc;
    }
    __syncthreads();

    float x = 0.f;
    if (t < 128) {
        x = er[t] + ypart[0][t] + ypart[1][t] + bo[t];
        float s1 = x, s2 = x * x;
        #pragma unroll
        for (int off = 32; off >= 1; off >>= 1) {
            s1 += __shfl_xor(s1, off, 64);
            s2 += __shfl_xor(s2, off, 64);
        }
        if ((t & 63) == 0) { red[(t >> 6) * 2] = s1; red[(t >> 6) * 2 + 1] = s2; }
    }
    __syncthreads();
    if (t < 128) {
        float mu  = (red[0] + red[2]) * (1.0f / 128.0f);
        float ms  = (red[1] + red[3]) * (1.0f / 128.0f);
        float var = fmaxf(ms - mu * mu, 0.0f);
        float rs  = rsqrtf(var + LN_EPS);
        outp[m * 128 + t] = (x - mu) * rs * gamma_[t] + beta_[t];
    }
}

// ---------------------------------------------------------------------------
extern "C" void kernel_launch(void* const* d_in, const int* in_sizes, int n_in,
                              void* d_out, int out_size, void* d_ws, size_t ws_size,
                              hipStream_t stream) {
    const float* entity    = (const float*)d_in[0];
    const int*   nidx      = (const int*)d_in[1];
    const int*   nrel      = (const int*)d_in[2];
    const int*   nmask     = (const int*)d_in[3];
    const float* Wq        = (const float*)d_in[4];
    const float* bq        = (const float*)d_in[5];
    const float* Wk        = (const float*)d_in[6];
    const float* bk        = (const float*)d_in[7];
    const float* Wv        = (const float*)d_in[8];
    const float* bv        = (const float*)d_in[9];
    const float* Wo        = (const float*)d_in[10];
    const float* bo        = (const float*)d_in[11];
    const float* rel_table = (const float*)d_in[12];
    const float* gamma_    = (const float*)d_in[13];
    const float* beta_     = (const float*)d_in[14];

    // ws layout:
    //   EKV (bf16) 8M     @ 0
    //   EQb (bf16) 4M     @ 8388608
    //   OATb(bf16) 4M     @ 12582912
    //   RKb (bf16) 60672  @ 16777216
    //   WqT/WkT/WvT/WoT 32K each @ 16837888
    char* ws = (char*)d_ws;
    unsigned short* EKV  = (unsigned short*)(ws + 0);
    unsigned short* EQb  = (unsigned short*)(ws + 8388608);
    unsigned short* OATb = (unsigned short*)(ws + 12582912);
    unsigned short* RKb  = (unsigned short*)(ws + 16777216);
    unsigned short* WqT  = (unsigned short*)(ws + 16837888);
    unsigned short* WkT  = (unsigned short*)(ws + 16870656);
    unsigned short* WvT  = (unsigned short*)(ws + 16903424);
    unsigned short* WoT  = (unsigned short*)(ws + 16936192);
    const size_t NEED = 16968960;

    if (ws_size >= NEED) {
        prep_w<<<dim3(32), 256, 0, stream>>>(Wq, Wk, Wv, Wo, WqT, WkT, WvT, WoT);
        gemm4_mfma<<<dim3(256, 4), 256, 0, stream>>>(
            entity, rel_table, WqT, WkT, WvT, bq, bk, bv, EQb, EKV, RKb);
        attn_gather<<<dim3(M_NODES / 4), 256, 0, stream>>>(
            nidx, nrel, nmask, EQb, EKV, RKb, OATb);
        gemm_wo_ln<<<dim3(256), 128, 0, stream>>>(
            OATb, WoT, bo, entity, gamma_, beta_, (float*)d_out);
    } else {
        rga_fused<<<dim3(M_NODES), 256, 0, stream>>>(
            entity, nidx, nrel, nmask, Wq, bq, Wk, bk, Wv, bv, Wo, bo,
            rel_table, gamma_, beta_, (float*)d_out);
    }
}